// Round 9
// baseline (15.825 us; speedup 1.0000x reference)
//
#include <hip/hip_runtime.h>

#define B_ 8
#define C_ 4
#define H_ 256
#define W_ 256
#define NIMG 32
#define HW 65536
#define RPB 8                     // rows per block (4 per thread-half)
#define NBLK (B_ * H_ / RPB)      // 256 blocks, 512 threads each
#define INF2 (1.0e6f * 1.0e6f)   // fl(1e12), same as reference capped scan squared

// One block per (b, 8 consecutive rows); 512 threads = 2 halves x 256 columns,
// each half owns 4 rows (identical per-thread body to the validated RPB=4
// version). Only the pixel's OWN class c=y[h][w] has a nontrivial EDT; other 3
// channels contribute p_c*1. Per block emit 9 partials:
// A_c = sum p*d, M_c = max d (c=0..3), T = sum (1-p_yv).
__global__ __launch_bounds__(512) void fused_kernel(const int* __restrict__ y,
                                                    const float* __restrict__ x,
                                                    float* __restrict__ P) {
    const int blk = blockIdx.x;          // b*32 + rb
    const int b = blk >> 5;
    const int tid = threadIdx.x;         // 0..511
    const int half = tid >> 8;           // 0: rows 0-3, 1: rows 4-7
    const int tx = tid & 255;            // column
    const int h0 = (blk & 31) * RPB + half * 4;   // first of this half's 4 rows
    const int* __restrict__ yb = y + b * HW;

    // ---- all independent loads upfront: 12 y-rows (h0-4..h0+7, clamped)
    // ---- and 16 x values (4 rows x 4 channels).
    int yr[12];
#pragma unroll
    for (int i = 0; i < 12; ++i) {
        const int hh = min(max(h0 - 4 + i, 0), H_ - 1);
        yr[i] = yb[hh * W_ + tx];
    }
    float xv[4][C_];
    const float* __restrict__ xb = x + (size_t)b * (C_ * HW) + h0 * W_ + tx;
#pragma unroll
    for (int r = 0; r < 4; ++r)
#pragma unroll
        for (int c = 0; c < C_; ++c) xv[r][c] = xb[c * HW + r * W_];

    // ---- column distance^2 per row: nearest row with a different label ----
    float g2v[4];
#pragma unroll
    for (int r = 0; r < 4; ++r) {
        const int yv = yr[4 + r];
        const int h = h0 + r;
        float g2 = INF2;
        bool done = false;
#pragma unroll
        for (int k = 1; k <= 4; ++k) {
            const bool hit = ((h - k >= 0) && yr[4 + r - k] != yv) ||
                             ((h + k < H_) && yr[4 + r + k] != yv);
            if (!done && hit) { g2 = (float)(k * k); done = true; }
        }
        if (__any(!done)) {              // rare: unresolved past k=4
            for (int k = 5; k < H_; ++k) {
                const int hu = h - k, hd = h + k;
                const int u = yb[max(hu, 0) * W_ + tx];
                const int dn = yb[min(hd, H_ - 1) * W_ + tx];
                const bool hit = ((hu >= 0) && u != yv) || ((hd < H_) && dn != yv);
                if (!done && hit) { g2 = (float)(k * k); done = true; }
                if (__all(done)) break;
                if (hu < 0 && hd >= H_) break;
            }
        }
        g2v[r] = g2;
    }

    __shared__ uint2 s2[RPB][W_];        // {g2 bits, label} per row
#pragma unroll
    for (int r = 0; r < 4; ++r)
        s2[half * 4 + r][tx] = make_uint2(__float_as_uint(g2v[r]), (unsigned)yr[4 + r]);
    __syncthreads();

    // ---- exact min-plus along W per row, adaptive radius, clamped indices ----
    // cand(j,k) = (label[j]==yv ? g2col[j] : 0) + k^2 ; a clamped j is
    // dominated by its true-k evaluation, so clamping never changes the min.
#define CAND(SR, CU, J, K2) ({ int j_ = (J); j_ = min(max(j_, 0), W_ - 1);     \
                               const uint2 v_ = (SR)[j_];                      \
                               (((v_.y == (CU)) ? __uint_as_float(v_.x) : 0.0f) + (K2)); })
    float mv[4];
#pragma unroll
    for (int r = 0; r < 4; ++r) {
        const unsigned cu = (unsigned)yr[4 + r];
        const uint2* sr = s2[half * 4 + r];
        float m = g2v[r];                // j = x candidate
        m = fminf(m, fminf(CAND(sr, cu, tx - 1, 1.0f),  CAND(sr, cu, tx + 1, 1.0f)));
        m = fminf(m, fminf(CAND(sr, cu, tx - 2, 4.0f),  CAND(sr, cu, tx + 2, 4.0f)));
        m = fminf(m, fminf(CAND(sr, cu, tx - 3, 9.0f),  CAND(sr, cu, tx + 3, 9.0f)));
        m = fminf(m, fminf(CAND(sr, cu, tx - 4, 16.0f), CAND(sr, cu, tx + 4, 16.0f)));
        mv[r] = m;
    }
#pragma unroll
    for (int r = 0; r < 4; ++r) {
        if (__any(mv[r] > 25.0f)) {      // some lane could still improve at k>=5
            const unsigned cu = (unsigned)yr[4 + r];
            const uint2* sr = s2[half * 4 + r];
            float m = mv[r];
            float k2 = 25.0f, tk1 = 11.0f;   // k^2, 2k+1 (exact ints in f32)
            for (int k = 5; k < W_; ++k) {
                m = fminf(m, fminf(CAND(sr, cu, tx - k, k2), CAND(sr, cu, tx + k, k2)));
                k2 += tk1; tk1 += 2.0f;
                if (__all(k2 >= m)) break;   // next k can't improve any lane
            }
            mv[r] = m;
        }
    }
#undef CAND

    // ---- softmax + contribution split, accumulated across the 4 rows ----
    float A[C_] = {0.f, 0.f, 0.f, 0.f};
    float M[C_] = {0.f, 0.f, 0.f, 0.f};
    float T = 0.0f;
#pragma unroll
    for (int r = 0; r < 4; ++r) {
        const int yv = yr[4 + r];
        const float d = sqrtf(mv[r]);    // own-class distance (>= 1)
        const float x0 = xv[r][0], x1 = xv[r][1], x2 = xv[r][2], x3 = xv[r][3];
        const float xm = fmaxf(fmaxf(x0, x1), fmaxf(x2, x3));
        const float e0 = __expf(x0 - xm), e1 = __expf(x1 - xm);
        const float e2 = __expf(x2 - xm), e3 = __expf(x3 - xm);
        const float se = e0 + e1 + e2 + e3;
        const float inv = 1.0f / se;
        const float ec = (yv == 0) ? e0 : (yv == 1) ? e1 : (yv == 2) ? e2 : e3;
        const float p = ec * inv;        // own-class probability
        T += (se - ec) * inv;            // other 3 classes: r = 1
        const float a = p * d;           // own class: needs /(mx+eps) later
#pragma unroll
        for (int c = 0; c < C_; ++c) {
            A[c] += (yv == c) ? a : 0.0f;
            M[c] = fmaxf(M[c], (yv == c) ? d : 0.0f);
        }
    }

    // ---- fixed-order wave butterfly + 8-wave cross combine (9 quantities) ----
#pragma unroll
    for (int off = 1; off < 64; off <<= 1) {
#pragma unroll
        for (int c = 0; c < C_; ++c) {
            A[c] += __shfl_xor(A[c], off);
            M[c] = fmaxf(M[c], __shfl_xor(M[c], off));
        }
        T += __shfl_xor(T, off);
    }
    __shared__ float red[8][9];
    const int wid = tid >> 6;
    if ((tid & 63) == 0) {
#pragma unroll
        for (int c = 0; c < C_; ++c) { red[wid][c] = A[c]; red[wid][4 + c] = M[c]; }
        red[wid][8] = T;
    }
    __syncthreads();
    if (tid < 9) {  // slots 0-3: A sums, 4-7: M maxes, 8: T sum (fixed order)
        float v = 0.0f;
        if (tid >= 4 && tid < 8) {
            v = red[0][tid];
#pragma unroll
            for (int wv = 1; wv < 8; ++wv) v = fmaxf(v, red[wv][tid]);
        } else {
            v = ((red[0][tid] + red[1][tid]) + (red[2][tid] + red[3][tid])) +
                ((red[4][tid] + red[5][tid]) + (red[6][tid] + red[7][tid]));
        }
        P[tid * NBLK + blk] = v;
    }
}

// Single block: P[slot][b*32+rb] -> out = (T - sum_{b,c} A/(M+1e-15)) / (B*C*H*W)
__global__ void finish_kernel(const float* __restrict__ P, float* __restrict__ out) {
    const int t = threadIdx.x;           // 256 threads; 32 groups of 8 = (b,c)
    const int g = t >> 3, l = t & 7;
    const int b = g >> 2, c = g & 3;
    const float* Pa = P + c * NBLK + b * 32;
    const float* Pm = P + (4 + c) * NBLK + b * 32;
    float a = 0.0f, mm = 0.0f;
#pragma unroll
    for (int i = 0; i < 4; ++i) {        // 32 partials per (b,c)
        a += Pa[l + (i << 3)];
        mm = fmaxf(mm, Pm[l + (i << 3)]);
    }
#pragma unroll
    for (int off = 1; off < 8; off <<= 1) {
        a += __shfl_xor(a, off);
        mm = fmaxf(mm, __shfl_xor(mm, off));
    }
    const float* Pt = P + 8 * NBLK;
    float tt = Pt[t];                    // 256 T-partials, one per thread
#pragma unroll
    for (int off = 1; off < 64; off <<= 1) tt += __shfl_xor(tt, off);
    __shared__ float sV[32];
    __shared__ float sT[4];
    if (l == 0) sV[g] = a / (mm + 1e-15f);
    if ((t & 63) == 0) sT[t >> 6] = tt;
    __syncthreads();
    if (t == 0) {
        float S = 0.0f;
#pragma unroll
        for (int i = 0; i < 32; ++i) S += sV[i];
        const float T = (sT[0] + sT[1]) + (sT[2] + sT[3]);
        out[0] = (T - S) * (1.0f / 2097152.0f);   // / (B*C*H*W)
    }
}

extern "C" void kernel_launch(void* const* d_in, const int* in_sizes, int n_in,
                              void* d_out, int out_size, void* d_ws, size_t ws_size,
                              hipStream_t stream) {
    const float* x = (const float*)d_in[0];   // [B, C, H, W] f32
    const int* y = (const int*)d_in[1];       // [B, 1, H, W] i32
    float* out = (float*)d_out;               // scalar f32
    float* P = (float*)d_ws;                  // [9][NBLK] partials (9 KB)

    fused_kernel<<<NBLK, 512, 0, stream>>>(y, x, P);
    finish_kernel<<<1, 256, 0, stream>>>(P, out);
}

// Round 10
// 15.021 us; speedup vs baseline: 1.0535x; 1.0535x over previous
//
#include <hip/hip_runtime.h>

#define B_ 8
#define C_ 4
#define H_ 256
#define W_ 256
#define NIMG 32
#define HW 65536
#define RPB 4                     // rows per block
#define NBLK (B_ * H_ / RPB)      // 512 blocks
#define INF2 (1.0e6f * 1.0e6f)   // fl(1e12), same as reference capped scan squared

// One block per (b, 4 consecutive rows). Only the pixel's OWN class c=y[h][w]
// has a nontrivial EDT; other 3 channels contribute p_c*1. Adjacent rows share
// the k<=4 neighbor window: 12 y-rows serve all 4 rows. Per block emit 9
// partials: A_c = sum p*d, M_c = max d (c=0..3), T = sum (1-p_yv).
// [round-8 champion config: 512 blocks x 256 thr = 2048 waves, measured 15.1us;
//  RPB=8/512thr measured 15.8us (worse); last-block atomics measured 55-66us
//  (same-address atomic serialization ~20ns each — never again on CDNA4).]
__global__ __launch_bounds__(256) void fused_kernel(const int* __restrict__ y,
                                                    const float* __restrict__ x,
                                                    float* __restrict__ P) {
    const int blk = blockIdx.x;          // b*64 + rb
    const int b = blk >> 6;
    const int h0 = (blk & 63) * RPB;     // first of 4 rows
    const int tx = threadIdx.x;          // column
    const int* __restrict__ yb = y + b * HW;

    // ---- all independent loads upfront: 12 y-rows (h0-4..h0+7, clamped)
    // ---- and 16 x values (4 rows x 4 channels).
    int yr[12];
#pragma unroll
    for (int i = 0; i < 12; ++i) {
        const int hh = min(max(h0 - 4 + i, 0), H_ - 1);
        yr[i] = yb[hh * W_ + tx];
    }
    float xv[RPB][C_];
    const float* __restrict__ xb = x + (size_t)b * (C_ * HW) + h0 * W_ + tx;
#pragma unroll
    for (int r = 0; r < RPB; ++r)
#pragma unroll
        for (int c = 0; c < C_; ++c) xv[r][c] = xb[c * HW + r * W_];

    // ---- column distance^2 per row: nearest row with a different label ----
    float g2v[RPB];
#pragma unroll
    for (int r = 0; r < RPB; ++r) {
        const int yv = yr[4 + r];
        const int h = h0 + r;
        float g2 = INF2;
        bool done = false;
#pragma unroll
        for (int k = 1; k <= 4; ++k) {
            const bool hit = ((h - k >= 0) && yr[4 + r - k] != yv) ||
                             ((h + k < H_) && yr[4 + r + k] != yv);
            if (!done && hit) { g2 = (float)(k * k); done = true; }
        }
        if (__any(!done)) {              // rare: unresolved past k=4
            for (int k = 5; k < H_; ++k) {
                const int hu = h - k, hd = h + k;
                const int u = yb[max(hu, 0) * W_ + tx];
                const int dn = yb[min(hd, H_ - 1) * W_ + tx];
                const bool hit = ((hu >= 0) && u != yv) || ((hd < H_) && dn != yv);
                if (!done && hit) { g2 = (float)(k * k); done = true; }
                if (__all(done)) break;
                if (hu < 0 && hd >= H_) break;
            }
        }
        g2v[r] = g2;
    }

    __shared__ uint2 s2[RPB][W_];        // {g2 bits, label} per row
#pragma unroll
    for (int r = 0; r < RPB; ++r)
        s2[r][tx] = make_uint2(__float_as_uint(g2v[r]), (unsigned)yr[4 + r]);
    __syncthreads();

    // ---- exact min-plus along W per row, adaptive radius, clamped indices ----
    // cand(j,k) = (label[j]==yv ? g2col[j] : 0) + k^2 ; a clamped j is
    // dominated by its true-k evaluation, so clamping never changes the min.
#define CAND(SR, CU, J, K2) ({ int j_ = (J); j_ = min(max(j_, 0), W_ - 1);     \
                               const uint2 v_ = (SR)[j_];                      \
                               (((v_.y == (CU)) ? __uint_as_float(v_.x) : 0.0f) + (K2)); })
    float mv[RPB];
#pragma unroll
    for (int r = 0; r < RPB; ++r) {
        const unsigned cu = (unsigned)yr[4 + r];
        const uint2* sr = s2[r];
        float m = g2v[r];                // j = x candidate
        m = fminf(m, fminf(CAND(sr, cu, tx - 1, 1.0f),  CAND(sr, cu, tx + 1, 1.0f)));
        m = fminf(m, fminf(CAND(sr, cu, tx - 2, 4.0f),  CAND(sr, cu, tx + 2, 4.0f)));
        m = fminf(m, fminf(CAND(sr, cu, tx - 3, 9.0f),  CAND(sr, cu, tx + 3, 9.0f)));
        m = fminf(m, fminf(CAND(sr, cu, tx - 4, 16.0f), CAND(sr, cu, tx + 4, 16.0f)));
        mv[r] = m;
    }
#pragma unroll
    for (int r = 0; r < RPB; ++r) {
        if (__any(mv[r] > 25.0f)) {      // some lane could still improve at k>=5
            const unsigned cu = (unsigned)yr[4 + r];
            const uint2* sr = s2[r];
            float m = mv[r];
            float k2 = 25.0f, tk1 = 11.0f;   // k^2, 2k+1 (exact ints in f32)
            for (int k = 5; k < W_; ++k) {
                m = fminf(m, fminf(CAND(sr, cu, tx - k, k2), CAND(sr, cu, tx + k, k2)));
                k2 += tk1; tk1 += 2.0f;
                if (__all(k2 >= m)) break;   // next k can't improve any lane
            }
            mv[r] = m;
        }
    }
#undef CAND

    // ---- softmax + contribution split, accumulated across the 4 rows ----
    float A[C_] = {0.f, 0.f, 0.f, 0.f};
    float M[C_] = {0.f, 0.f, 0.f, 0.f};
    float T = 0.0f;
#pragma unroll
    for (int r = 0; r < RPB; ++r) {
        const int yv = yr[4 + r];
        const float d = sqrtf(mv[r]);    // own-class distance (>= 1)
        const float x0 = xv[r][0], x1 = xv[r][1], x2 = xv[r][2], x3 = xv[r][3];
        const float xm = fmaxf(fmaxf(x0, x1), fmaxf(x2, x3));
        const float e0 = __expf(x0 - xm), e1 = __expf(x1 - xm);
        const float e2 = __expf(x2 - xm), e3 = __expf(x3 - xm);
        const float se = e0 + e1 + e2 + e3;
        const float inv = 1.0f / se;
        const float ec = (yv == 0) ? e0 : (yv == 1) ? e1 : (yv == 2) ? e2 : e3;
        const float p = ec * inv;        // own-class probability
        T += (se - ec) * inv;            // other 3 classes: r = 1
        const float a = p * d;           // own class: needs /(mx+eps) later
#pragma unroll
        for (int c = 0; c < C_; ++c) {
            A[c] += (yv == c) ? a : 0.0f;
            M[c] = fmaxf(M[c], (yv == c) ? d : 0.0f);
        }
    }

    // ---- fixed-order wave butterfly + cross-wave combine (9 quantities) ----
#pragma unroll
    for (int off = 1; off < 64; off <<= 1) {
#pragma unroll
        for (int c = 0; c < C_; ++c) {
            A[c] += __shfl_xor(A[c], off);
            M[c] = fmaxf(M[c], __shfl_xor(M[c], off));
        }
        T += __shfl_xor(T, off);
    }
    __shared__ float red[4][9];
    const int wid = tx >> 6;
    if ((tx & 63) == 0) {
#pragma unroll
        for (int c = 0; c < C_; ++c) { red[wid][c] = A[c]; red[wid][4 + c] = M[c]; }
        red[wid][8] = T;
    }
    __syncthreads();
    if (tx < 9) {   // slots 0-3: A sums, 4-7: M maxes, 8: T sum
        const float v0 = red[0][tx], v1 = red[1][tx], v2 = red[2][tx], v3 = red[3][tx];
        const float r = (tx >= 4 && tx < 8) ? fmaxf(fmaxf(v0, v1), fmaxf(v2, v3))
                                            : (v0 + v1) + (v2 + v3);
        P[tx * NBLK + blk] = r;
    }
}

// Single block: P[slot][b*64+rb] -> out = (T - sum_{b,c} A/(M+1e-15)) / (B*C*H*W)
__global__ void finish_kernel(const float* __restrict__ P, float* __restrict__ out) {
    const int t = threadIdx.x;           // 256 threads; 32 groups of 8 = (b,c)
    const int g = t >> 3, l = t & 7;
    const int b = g >> 2, c = g & 3;
    const float* Pa = P + c * NBLK + b * 64;
    const float* Pm = P + (4 + c) * NBLK + b * 64;
    float a = 0.0f, mm = 0.0f;
#pragma unroll
    for (int i = 0; i < 8; ++i) {        // 64 partials per (b,c)
        a += Pa[l + (i << 3)];
        mm = fmaxf(mm, Pm[l + (i << 3)]);
    }
#pragma unroll
    for (int off = 1; off < 8; off <<= 1) {
        a += __shfl_xor(a, off);
        mm = fmaxf(mm, __shfl_xor(mm, off));
    }
    const float* Pt = P + 8 * NBLK;
    float tt = Pt[t] + Pt[t + 256];
#pragma unroll
    for (int off = 1; off < 64; off <<= 1) tt += __shfl_xor(tt, off);
    __shared__ float sV[32];
    __shared__ float sT[4];
    if (l == 0) sV[g] = a / (mm + 1e-15f);
    if ((t & 63) == 0) sT[t >> 6] = tt;
    __syncthreads();
    if (t == 0) {
        float S = 0.0f;
#pragma unroll
        for (int i = 0; i < 32; ++i) S += sV[i];
        const float T = (sT[0] + sT[1]) + (sT[2] + sT[3]);
        out[0] = (T - S) * (1.0f / 2097152.0f);   // / (B*C*H*W)
    }
}

extern "C" void kernel_launch(void* const* d_in, const int* in_sizes, int n_in,
                              void* d_out, int out_size, void* d_ws, size_t ws_size,
                              hipStream_t stream) {
    const float* x = (const float*)d_in[0];   // [B, C, H, W] f32
    const int* y = (const int*)d_in[1];       // [B, 1, H, W] i32
    float* out = (float*)d_out;               // scalar f32
    float* P = (float*)d_ws;                  // [9][NBLK] partials (18 KB)

    fused_kernel<<<NBLK, 256, 0, stream>>>(y, x, P);
    finish_kernel<<<1, 256, 0, stream>>>(P, out);
}